// Round 10
// baseline (192.220 us; speedup 1.0000x reference)
//
#include <hip/hip_runtime.h>
#include <math.h>

#define NN 8192
#define DD 64
#define EE 64
#define NB 2
#define THRESH 0.7f
#define ISPLIT 8
#define ISPAN (NN / ISPLIT)   // 1024
#define NIT (ISPAN / 16)      // 64 iterations of 16 i
#define LOG2E 1.4426950408889634f

typedef __attribute__((ext_vector_type(8))) short bf16x8;
typedef __attribute__((ext_vector_type(4))) float f32x4;
typedef _Float16 f16x4 __attribute__((ext_vector_type(4)));
typedef __fp16 half2v __attribute__((ext_vector_type(2)));

static __device__ __forceinline__ short f2bf(float x) {  // RNE
    unsigned u = __float_as_uint(x);
    unsigned r = (u + 0x7fffu + ((u >> 16) & 1u)) >> 16;
    return (short)r;
}
static __device__ __forceinline__ unsigned pk_f16(float a, float b) {
    half2v h = __builtin_amdgcn_cvt_pkrtz(a, b);
    return __builtin_bit_cast(unsigned, h);
}
static __device__ __forceinline__ float f16lo(unsigned u) {
    half2v h = __builtin_bit_cast(half2v, u);
    return (float)h[0];
}
static __device__ __forceinline__ float f16hi(unsigned u) {
    half2v h = __builtin_bit_cast(half2v, u);
    return (float)h[1];
}

// ---------------------------------------------------------------------------
// Prep: blocks [0,128): P = U@W via MFMA + U -> bf16 (round-8 verified).
//       blocks [128,256): es16f FRAGMENT-MAJOR for K=16 f16 B-frags:
//       es16f[((c16*8+g)*64 + lane)*4 + e] = es[bd=16g+(lane&15)][i=16c16+4*(lane>>4)+e]
//       -> transfer's loadE reads 512B contiguous per instruction (fixes the
//       16KB-stride gather that killed round 6).
// ---------------------------------------------------------------------------
__global__ __launch_bounds__(256) void prep_kernel(const float* __restrict__ U,
                                                   const float* __restrict__ W,
                                                   const float* __restrict__ S,
                                                   const float* __restrict__ prof,
                                                   short* __restrict__ P_bf,
                                                   short* __restrict__ U_bf,
                                                   _Float16* __restrict__ es16f) {
    __shared__ float smem[64 * 132 + 128];  // 34.3 KB (covers both roles)
    const int t = threadIdx.x;
    const f32x4 zero = (f32x4){0.f, 0.f, 0.f, 0.f};

    if (blockIdx.x < 128) {
        // ---- P = U@W with 16x16x32 bf16 MFMA ----
        float* WT = smem;  // [64][68] transposed W (+68 pad: 2-way alias only)
        for (int x = 0; x < 16; ++x) {
            const int idx = x * 256 + t;     // idx = k*64 + f
            const int k = idx >> 6, f = idx & 63;
            WT[f * 68 + k] = W[idx];
        }
        __syncthreads();

        const int w = t >> 6, lane = t & 63, q = lane >> 4, ln = lane & 15;
        const int r0 = blockIdx.x * 64 + w * 16;

        bf16x8 a[2];
#pragma unroll
        for (int ks = 0; ks < 2; ++ks) {
            const float4 u0 = *(const float4*)(U + (r0 + ln) * EE + ks * 32 + q * 8);
            const float4 u1 = *(const float4*)(U + (r0 + ln) * EE + ks * 32 + q * 8 + 4);
            bf16x8 v;
            v[0] = f2bf(u0.x); v[1] = f2bf(u0.y); v[2] = f2bf(u0.z); v[3] = f2bf(u0.w);
            v[4] = f2bf(u1.x); v[5] = f2bf(u1.y); v[6] = f2bf(u1.z); v[7] = f2bf(u1.w);
            a[ks] = v;
            *(bf16x8*)(U_bf + (r0 + ln) * EE + ks * 32 + q * 8) = v;
        }
        bf16x8 b[4][2];
#pragma unroll
        for (int ct = 0; ct < 4; ++ct)
#pragma unroll
            for (int ks = 0; ks < 2; ++ks) {
                const float* wp = WT + (ct * 16 + ln) * 68 + ks * 32 + q * 8;
                const float4 w0 = *(const float4*)wp;
                const float4 w1 = *(const float4*)(wp + 4);
                bf16x8 v;
                v[0] = f2bf(w0.x); v[1] = f2bf(w0.y); v[2] = f2bf(w0.z); v[3] = f2bf(w0.w);
                v[4] = f2bf(w1.x); v[5] = f2bf(w1.y); v[6] = f2bf(w1.z); v[7] = f2bf(w1.w);
                b[ct][ks] = v;
            }
#pragma unroll
        for (int ct = 0; ct < 4; ++ct) {
            f32x4 s = __builtin_amdgcn_mfma_f32_16x16x32_bf16(a[0], b[ct][0], zero, 0, 0, 0);
            s = __builtin_amdgcn_mfma_f32_16x16x32_bf16(a[1], b[ct][1], s, 0, 0, 0);
#pragma unroll
            for (int r = 0; r < 4; ++r)
                P_bf[(r0 + 4 * q + r) * EE + ct * 16 + ln] = f2bf(s[r]);
        }
    } else {
        float* tr = smem;           // [64][132]
        float* gl = smem + 8448;    // [128]
        const int bi = blockIdx.x - 128;  // 0..127
        const int b = bi >> 6;
        const int i0 = (bi & 63) * 128;
        if (t < 128) gl[t] = fmaxf(prof[b * NN + i0 + t] - THRESH, 0.f);
        __syncthreads();
#pragma unroll
        for (int k = 0; k < 8; ++k) {
            const int idx = k * 256 + t;  // 2048 = 128 i x 16 c4
            const int i = idx >> 4, c4 = idx & 15;
            const float g = gl[i];
            const float4 s = ((const float4*)S)[(b * NN + i0 + i) * 16 + c4];
            tr[(c4 * 4 + 0) * 132 + i] = s.x * g;
            tr[(c4 * 4 + 1) * 132 + i] = s.y * g;
            tr[(c4 * 4 + 2) * 132 + i] = s.z * g;
            tr[(c4 * 4 + 3) * 132 + i] = s.w * g;
        }
        __syncthreads();
#pragma unroll
        for (int pass = 0; pass < 4; ++pass) {
            const int d = pass * 16 + (t >> 4);   // within-b row 0..63
            const int i8 = t & 15;                // 8-element i-group 0..15
            const float4 a = *(const float4*)&tr[d * 132 + i8 * 8];
            const float4 c = *(const float4*)&tr[d * 132 + i8 * 8 + 4];
            // fragment-major for K=16 f16 B-frag
            const int g   = b * 4 + (d >> 4);
            const int c16 = (i0 >> 4) + (i8 >> 1);
            const int q0  = 2 * (i8 & 1);
            _Float16* base = es16f + ((size_t)(c16 * 8 + g) * 64 + q0 * 16 + (d & 15)) * 4;
            uint2 v0, v1;
            v0.x = pk_f16(a.x, a.y); v0.y = pk_f16(a.z, a.w);
            v1.x = pk_f16(c.x, c.y); v1.y = pk_f16(c.z, c.w);
            *(uint2*)base = v0;          // q = q0,   e = 0..3
            *(uint2*)(base + 64) = v1;   // q = q0+1, e = 0..3
        }
    }
}

// ---------------------------------------------------------------------------
// Transfer: BARRIER-FREE (round-6 structure, es layout fixed). Each wave owns
// one 16-j tile; iterates 16-i chunks; K=16 f16 MFMA consumes T's D-layout
// lane-locally. No LDS, no sync; waves fully independent.
// Grid (128, ISPLIT=8) -> 1024 blocks x 4 waves.
// ---------------------------------------------------------------------------
__global__ __launch_bounds__(256, 3) void transfer_kernel(const short* __restrict__ P_bf,
                                                          const short* __restrict__ U_bf,
                                                          const _Float16* __restrict__ es16f,
                                                          const float* __restrict__ bias_p,
                                                          unsigned short* __restrict__ part) {
    const int t = threadIdx.x;
    const int w = t >> 6;
    const int lane = t & 63;
    const int q = lane >> 4;
    const int ln = lane & 15;
    const int jw0 = blockIdx.x * 64 + w * 16;   // this wave's j-tile
    const int i_base = blockIdx.y * ISPAN;
    const int c16_base = i_base >> 4;
    const float nb = -bias_p[0] * LOG2E;
    const f32x4 zero = (f32x4){0.f, 0.f, 0.f, 0.f};

    // U B-fragments for own j-tile (T-scores mfma, K=64 via 2x K=32)
    bf16x8 uf[2];
#pragma unroll
    for (int ks = 0; ks < 2; ++ks)
        uf[ks] = *(const bf16x8*)(U_bf + (jw0 + ln) * EE + ks * 32 + q * 8);

    // leaked accumulators: acc[g] lane: (j = jw0+4q+r, bd = 16g+ln)
    f32x4 acc[8];
#pragma unroll
    for (int g = 0; g < 8; ++g) acc[g] = zero;

    f16x4 esf[8];

    auto loadP = [&](int c, bf16x8* pf) {
        const int ic = i_base + c * 16;
#pragma unroll
        for (int ks = 0; ks < 2; ++ks)
            pf[ks] = *(const bf16x8*)(P_bf + (ic + ln) * EE + ks * 32 + q * 8);
    };
    auto loadE = [&](int c) {
        const _Float16* ep = es16f + ((size_t)(c16_base + c) * 8) * 256;
#pragma unroll
        for (int g = 0; g < 8; ++g)
            esf[g] = *(const f16x4*)(ep + (g * 64 + lane) * 4);  // 512B/instr
    };
    auto body = [&](int c, const bf16x8* pf) {
        const int ic = i_base + c * 16;
        // T tile: lane holds T[i=ic+4q+r, j=jw0+ln], r=0..3
        f32x4 s = __builtin_amdgcn_mfma_f32_16x16x32_bf16(pf[0], uf[0], zero, 0, 0, 0);
        s = __builtin_amdgcn_mfma_f32_16x16x32_bf16(pf[1], uf[1], s, 0, 0, 0);
        float T[4];
#pragma unroll
        for (int r = 0; r < 4; ++r)
            T[r] = __builtin_amdgcn_rcpf(
                1.f + __builtin_amdgcn_exp2f(fmaf(s[r], -LOG2E, nb)));
        if (ic == jw0) {  // diagonal tile (wave-uniform): zero i==j
            const int dd = ln - 4 * q;
#pragma unroll
            for (int r = 0; r < 4; ++r) T[r] = (dd == r) ? 0.f : T[r];
        }
        // pack -> fp16 A-frag for K=16 mfma (lane-local transpose!)
        uint2 pw;
        pw.x = pk_f16(T[0], T[1]);
        pw.y = pk_f16(T[2], T[3]);
        const f16x4 pa = __builtin_bit_cast(f16x4, pw);
#pragma unroll
        for (int g = 0; g < 8; ++g)
            acc[g] = __builtin_amdgcn_mfma_f32_16x16x16f16(pa, esf[g], acc[g], 0, 0, 0);
    };

    // ping-pong on pf (static names, rule #20); es loaded per-iter ahead of
    // body: T-phase MFMA+sigmoid covers the (now coalesced) load latency.
    bf16x8 pfa[2], pfb[2];
    loadP(0, pfa);
    for (int c = 0; c < NIT; c += 2) {
        loadE(c);
        loadP(c + 1, pfb);
        body(c, pfa);
        loadE(c + 1);
        if (c + 2 < NIT) loadP(c + 2, pfa);
        body(c + 1, pfb);
    }

    // epilogue: fp16 partials, 4KB tile per (y, jt); fully coalesced.
    const int jt = blockIdx.x * 4 + w;
    unsigned short* pb = part + (size_t)(blockIdx.y * 512 + jt) * 2048;
#pragma unroll
    for (int k = 0; k < 4; ++k) {
        uint4 v;
        v.x = pk_f16(acc[2 * k][0], acc[2 * k][1]);
        v.y = pk_f16(acc[2 * k][2], acc[2 * k][3]);
        v.z = pk_f16(acc[2 * k + 1][0], acc[2 * k + 1][1]);
        v.w = pk_f16(acc[2 * k + 1][2], acc[2 * k + 1][3]);
        *(uint4*)(pb + k * 512 + lane * 8) = v;
    }
}

// ---------------------------------------------------------------------------
// Reduce: out[b][j][d] = S + sum_y part. One block per 16-j tile (512 blocks).
// (round-6-verified variant)
// ---------------------------------------------------------------------------
__global__ __launch_bounds__(256) void reduce_kernel(const unsigned short* __restrict__ part,
                                                     const float* __restrict__ S,
                                                     float* __restrict__ out) {
    const int t = threadIdx.x;
    const int jt = blockIdx.x;   // 0..511
    const int l = t & 63, k = t >> 6;
    const int q = l >> 4, ln = l & 15;

    float acc[4][2];
#pragma unroll
    for (int c = 0; c < 4; ++c) {
        acc[c][0] = 0.f;
        acc[c][1] = 0.f;
    }

#pragma unroll
    for (int y = 0; y < ISPLIT; ++y) {
        const uint4 v = *(const uint4*)(part + (size_t)(y * 512 + jt) * 2048 + k * 512 + l * 8);
        acc[0][0] += f16lo(v.x); acc[0][1] += f16hi(v.x);
        acc[1][0] += f16lo(v.y); acc[1][1] += f16hi(v.y);
        acc[2][0] += f16lo(v.z); acc[2][1] += f16hi(v.z);
        acc[3][0] += f16lo(v.w); acc[3][1] += f16hi(v.w);
    }
#pragma unroll
    for (int c = 0; c < 4; ++c) {
        const int g = 2 * k + (c >> 1);
        const int bd = 16 * g + ln;
        const int b = bd >> 6, d = bd & 63;
#pragma unroll
        for (int h = 0; h < 2; ++h) {
            const int j = jt * 16 + 4 * q + 2 * (c & 1) + h;
            const int idx = (b * NN + j) * DD + d;
            out[idx] = S[idx] + acc[c][h];
        }
    }
}

// ---------------------------------------------------------------------------
extern "C" void kernel_launch(void* const* d_in, const int* in_sizes, int n_in,
                              void* d_out, int out_size, void* d_ws, size_t ws_size,
                              hipStream_t stream) {
    const float* states = (const float*)d_in[0];  // [B,N,D]
    const float* prof   = (const float*)d_in[1];  // [B,N]
    const float* emb    = (const float*)d_in[2];  // [N,E]
    const float* W      = (const float*)d_in[3];  // [1,E,E]
    const float* bias   = (const float*)d_in[4];  // [1]
    float* out = (float*)d_out;

    short* P_bf = (short*)d_ws;                   // 1 MB
    short* U_bf = P_bf + NN * EE;                 // 1 MB
    _Float16* es16f = (_Float16*)(U_bf + NN * EE);  // 2 MB (fragment-major fp16)
    unsigned short* part = (unsigned short*)((short*)es16f + (size_t)NB * 64 * NN);  // 16.8 MB

    prep_kernel<<<256, 256, 0, stream>>>(emb, W, states, prof, P_bf, U_bf, es16f);
    transfer_kernel<<<dim3(NN / 64, ISPLIT), 256, 0, stream>>>(P_bf, U_bf, es16f, bias, part);
    reduce_kernel<<<512, 256, 0, stream>>>(part, states, out);
}

// Round 11
// 117.877 us; speedup vs baseline: 1.6307x; 1.6307x over previous
//
#include <hip/hip_runtime.h>
#include <math.h>

#define NN 8192
#define DD 64
#define EE 64
#define NB 2
#define THRESH 0.7f
#define ISPLIT 4
#define ISPAN (NN / ISPLIT)   // 2048
#define LOG2E 1.4426950408889634f

typedef __attribute__((ext_vector_type(8))) short bf16x8;
typedef __attribute__((ext_vector_type(4))) float f32x4;
typedef _Float16 f16x4 __attribute__((ext_vector_type(4)));
typedef _Float16 f16x8 __attribute__((ext_vector_type(8)));
typedef __fp16 half2v __attribute__((ext_vector_type(2)));

static __device__ __forceinline__ short f2bf(float x) {  // RNE
    unsigned u = __float_as_uint(x);
    unsigned r = (u + 0x7fffu + ((u >> 16) & 1u)) >> 16;
    return (short)r;
}
static __device__ __forceinline__ unsigned pk_f16(float a, float b) {
    half2v h = __builtin_amdgcn_cvt_pkrtz(a, b);
    return __builtin_bit_cast(unsigned, h);
}
static __device__ __forceinline__ float f16lo(unsigned u) {
    half2v h = __builtin_bit_cast(half2v, u);
    return (float)h[0];
}
static __device__ __forceinline__ float f16hi(unsigned u) {
    half2v h = __builtin_bit_cast(half2v, u);
    return (float)h[1];
}

// ---------------------------------------------------------------------------
// Prep: blocks [0,128): P = U@W via MFMA + U -> bf16 (round-8 verified).
//       blocks [128,256): es16f fragment-major, g-PAIRED for 16B/lane loads:
//       es16f[((c16*4+gp)*64 + lane)*8 + (g&1)*4 + e] = es[16g+(lane&15)][16c16+4*(lane>>4)+e]
// ---------------------------------------------------------------------------
__global__ __launch_bounds__(256) void prep_kernel(const float* __restrict__ U,
                                                   const float* __restrict__ W,
                                                   const float* __restrict__ S,
                                                   const float* __restrict__ prof,
                                                   short* __restrict__ P_bf,
                                                   short* __restrict__ U_bf,
                                                   _Float16* __restrict__ es16f) {
    __shared__ float smem[64 * 132 + 128];  // 34.3 KB (covers both roles)
    const int t = threadIdx.x;
    const f32x4 zero = (f32x4){0.f, 0.f, 0.f, 0.f};

    if (blockIdx.x < 128) {
        // ---- P = U@W with 16x16x32 bf16 MFMA ----
        float* WT = smem;  // [64][68] transposed W (+68 pad: 2-way alias only)
        for (int x = 0; x < 16; ++x) {
            const int idx = x * 256 + t;     // idx = k*64 + f
            const int k = idx >> 6, f = idx & 63;
            WT[f * 68 + k] = W[idx];
        }
        __syncthreads();

        const int w = t >> 6, lane = t & 63, q = lane >> 4, ln = lane & 15;
        const int r0 = blockIdx.x * 64 + w * 16;

        bf16x8 a[2];
#pragma unroll
        for (int ks = 0; ks < 2; ++ks) {
            const float4 u0 = *(const float4*)(U + (r0 + ln) * EE + ks * 32 + q * 8);
            const float4 u1 = *(const float4*)(U + (r0 + ln) * EE + ks * 32 + q * 8 + 4);
            bf16x8 v;
            v[0] = f2bf(u0.x); v[1] = f2bf(u0.y); v[2] = f2bf(u0.z); v[3] = f2bf(u0.w);
            v[4] = f2bf(u1.x); v[5] = f2bf(u1.y); v[6] = f2bf(u1.z); v[7] = f2bf(u1.w);
            a[ks] = v;
            *(bf16x8*)(U_bf + (r0 + ln) * EE + ks * 32 + q * 8) = v;
        }
        bf16x8 b[4][2];
#pragma unroll
        for (int ct = 0; ct < 4; ++ct)
#pragma unroll
            for (int ks = 0; ks < 2; ++ks) {
                const float* wp = WT + (ct * 16 + ln) * 68 + ks * 32 + q * 8;
                const float4 w0 = *(const float4*)wp;
                const float4 w1 = *(const float4*)(wp + 4);
                bf16x8 v;
                v[0] = f2bf(w0.x); v[1] = f2bf(w0.y); v[2] = f2bf(w0.z); v[3] = f2bf(w0.w);
                v[4] = f2bf(w1.x); v[5] = f2bf(w1.y); v[6] = f2bf(w1.z); v[7] = f2bf(w1.w);
                b[ct][ks] = v;
            }
#pragma unroll
        for (int ct = 0; ct < 4; ++ct) {
            f32x4 s = __builtin_amdgcn_mfma_f32_16x16x32_bf16(a[0], b[ct][0], zero, 0, 0, 0);
            s = __builtin_amdgcn_mfma_f32_16x16x32_bf16(a[1], b[ct][1], s, 0, 0, 0);
#pragma unroll
            for (int r = 0; r < 4; ++r)
                P_bf[(r0 + 4 * q + r) * EE + ct * 16 + ln] = f2bf(s[r]);
        }
    } else {
        float* tr = smem;           // [64][132]
        float* gl = smem + 8448;    // [128]
        const int bi = blockIdx.x - 128;  // 0..127
        const int b = bi >> 6;
        const int i0 = (bi & 63) * 128;
        if (t < 128) gl[t] = fmaxf(prof[b * NN + i0 + t] - THRESH, 0.f);
        __syncthreads();
#pragma unroll
        for (int k = 0; k < 8; ++k) {
            const int idx = k * 256 + t;  // 2048 = 128 i x 16 c4
            const int i = idx >> 4, c4 = idx & 15;
            const float g = gl[i];
            const float4 s = ((const float4*)S)[(b * NN + i0 + i) * 16 + c4];
            tr[(c4 * 4 + 0) * 132 + i] = s.x * g;
            tr[(c4 * 4 + 1) * 132 + i] = s.y * g;
            tr[(c4 * 4 + 2) * 132 + i] = s.z * g;
            tr[(c4 * 4 + 3) * 132 + i] = s.w * g;
        }
        __syncthreads();
#pragma unroll
        for (int pass = 0; pass < 4; ++pass) {
            const int d = pass * 16 + (t >> 4);   // within-b row 0..63
            const int i8 = t & 15;                // 8-element i-group 0..15
            const float4 a = *(const float4*)&tr[d * 132 + i8 * 8];
            const float4 c = *(const float4*)&tr[d * 132 + i8 * 8 + 4];
            const int g   = b * 4 + (d >> 4);
            const int c16 = (i0 >> 4) + (i8 >> 1);
            const int q0  = 2 * (i8 & 1);
            const int gp  = g >> 1, glo = g & 1;
            _Float16* base = es16f +
                ((size_t)((c16 * 4 + gp) * 64 + q0 * 16 + (d & 15))) * 8 + glo * 4;
            uint2 v0, v1;
            v0.x = pk_f16(a.x, a.y); v0.y = pk_f16(a.z, a.w);
            v1.x = pk_f16(c.x, c.y); v1.y = pk_f16(c.z, c.w);
            *(uint2*)base = v0;           // q = q0
            *(uint2*)(base + 128) = v1;   // q = q0+1
        }
    }
}

// ---------------------------------------------------------------------------
// Transfer v3: BARRIER-FREE + NON-REDUNDANT. Block owns 64 j; its 4 waves
// partition the i-chunks (c = w mod 4) -> R7's load economy with R6/R10's
// lane-local K=16 T-consumption (no LDS, no sync). Each wave accumulates the
// FULL 64j x 128bd tile (128 VGPR) for its i-subset; per-wave fp16 partial.
// Grid (128, ISPLIT=4) = 512 blocks x 4 waves = 2 blocks/CU (VGPR-matched).
// ---------------------------------------------------------------------------
__global__ __launch_bounds__(256, 2) void transfer_kernel(const short* __restrict__ P_bf,
                                                          const short* __restrict__ U_bf,
                                                          const _Float16* __restrict__ es16f,
                                                          const float* __restrict__ bias_p,
                                                          unsigned short* __restrict__ part) {
    const int t = threadIdx.x;
    const int w = t >> 6;
    const int lane = t & 63;
    const int q = lane >> 4;
    const int ln = lane & 15;
    const int j0 = blockIdx.x * 64;
    const int i_base = blockIdx.y * ISPAN;
    const int c16_base = i_base >> 4;
    const float nb = -bias_p[0] * LOG2E;
    const f32x4 zero = (f32x4){0.f, 0.f, 0.f, 0.f};

    // U B-fragments for all 4 j-tiles
    bf16x8 uf[4][2];
#pragma unroll
    for (int jt = 0; jt < 4; ++jt)
#pragma unroll
        for (int ks = 0; ks < 2; ++ks)
            uf[jt][ks] = *(const bf16x8*)(U_bf + (j0 + jt * 16 + ln) * EE + ks * 32 + q * 8);

    // acc[jt][g] lane(q,ln): leaked[j = j0+jt*16+4q+r][bd = 16g+ln]
    f32x4 acc[4][8];
#pragma unroll
    for (int jt = 0; jt < 4; ++jt)
#pragma unroll
        for (int g = 0; g < 8; ++g) acc[jt][g] = zero;

    auto loadP = [&](int c, bf16x8* pf) {
        const int ic = i_base + c * 16;
#pragma unroll
        for (int ks = 0; ks < 2; ++ks)
            pf[ks] = *(const bf16x8*)(P_bf + (ic + ln) * EE + ks * 32 + q * 8);
    };
    auto loadE = [&](int c, uint4* ef) {
        const _Float16* ep = es16f + (size_t)(c16_base + c) * 2048;
#pragma unroll
        for (int gp = 0; gp < 4; ++gp)
            ef[gp] = *(const uint4*)(ep + gp * 512 + lane * 8);  // 1KB/instr
    };
    auto body = [&](int c, const bf16x8* pf, const uint4* ef) {
        const int ic = i_base + c * 16;
        const int doff = ic - j0;
        const bool dg = (unsigned)doff < 64u;
        const int djt = doff >> 4;
        f16x4 esf[8];
#pragma unroll
        for (int gp = 0; gp < 4; ++gp) {
            const f16x8 full = __builtin_bit_cast(f16x8, ef[gp]);
            esf[2 * gp]     = __builtin_shufflevector(full, full, 0, 1, 2, 3);
            esf[2 * gp + 1] = __builtin_shufflevector(full, full, 4, 5, 6, 7);
        }
#pragma unroll
        for (int jt = 0; jt < 4; ++jt) {
            f32x4 s = __builtin_amdgcn_mfma_f32_16x16x32_bf16(pf[0], uf[jt][0], zero, 0, 0, 0);
            s = __builtin_amdgcn_mfma_f32_16x16x32_bf16(pf[1], uf[jt][1], s, 0, 0, 0);
            float T[4];
#pragma unroll
            for (int r = 0; r < 4; ++r)
                T[r] = __builtin_amdgcn_rcpf(
                    1.f + __builtin_amdgcn_exp2f(fmaf(s[r], -LOG2E, nb)));
            if (dg && jt == djt) {  // diagonal 16x16 sub-tile: zero i==j
                const int dd = ln - 4 * q;
#pragma unroll
                for (int r = 0; r < 4; ++r) T[r] = (dd == r) ? 0.f : T[r];
            }
            uint2 pw;
            pw.x = pk_f16(T[0], T[1]);
            pw.y = pk_f16(T[2], T[3]);
            const f16x4 pa = __builtin_bit_cast(f16x4, pw);
#pragma unroll
            for (int g = 0; g < 8; ++g)
                acc[jt][g] = __builtin_amdgcn_mfma_f32_16x16x16f16(pa, esf[g], acc[jt][g], 0, 0, 0);
        }
    };

    // wave handles chunks c = w, w+4, ..., w+508/4... : 32 chunks; ping-pong.
    const int NCHW = (ISPAN / 16) / 4;  // 32
    bf16x8 pfa[2], pfb[2];
    uint4 efa[4], efb[4];
    int c = w;
    loadP(c, pfa);
    loadE(c, efa);
    for (int it = 0; it < NCHW; it += 2) {
        loadP(c + 4, pfb);
        loadE(c + 4, efb);
        body(c, pfa, efa);
        if (it + 2 < NCHW) {
            loadP(c + 8, pfa);
            loadE(c + 8, efa);
        }
        body(c + 4, pfb, efb);
        c += 8;
    }

    // epilogue: per-wave fp16 partial tile [4jt][8g][64lane][4r], coalesced.
    unsigned short* pb = part +
        (size_t)(((blockIdx.y * 128 + blockIdx.x) * 4) + w) * 8192;
#pragma unroll
    for (int jt = 0; jt < 4; ++jt)
#pragma unroll
        for (int g = 0; g < 8; ++g) {
            uint2 v;
            v.x = pk_f16(acc[jt][g][0], acc[jt][g][1]);
            v.y = pk_f16(acc[jt][g][2], acc[jt][g][3]);
            *(uint2*)(pb + ((jt * 8 + g) * 64 + lane) * 4) = v;
        }
}

// ---------------------------------------------------------------------------
// Reduce: out = S + sum over 16 wave-tiles (4y x 4w) per jx.
// grid (128, 4): blockIdx.y = g-pair group (2 g's per block). 512 blocks.
// ---------------------------------------------------------------------------
__global__ __launch_bounds__(256) void reduce_kernel(const unsigned short* __restrict__ part,
                                                     const float* __restrict__ S,
                                                     float* __restrict__ out) {
    const int t = threadIdx.x;
    const int jx = blockIdx.x;        // 0..127
    const int gh = blockIdx.y;        // 0..3 -> g = 2gh, 2gh+1
    const int lane = t & 63, jt = t >> 6;
    const int q = lane >> 4, ln = lane & 15;

    float acc[2][4];
#pragma unroll
    for (int u = 0; u < 2; ++u)
#pragma unroll
        for (int r = 0; r < 4; ++r) acc[u][r] = 0.f;

#pragma unroll
    for (int y = 0; y < ISPLIT; ++y)
#pragma unroll
        for (int wv = 0; wv < 4; ++wv) {
            const unsigned short* pb = part +
                (size_t)(((y * 128 + jx) * 4) + wv) * 8192;
#pragma unroll
            for (int u = 0; u < 2; ++u) {
                const int g = gh * 2 + u;
                const uint2 v = *(const uint2*)(pb + ((jt * 8 + g) * 64 + lane) * 4);
                acc[u][0] += f16lo(v.x); acc[u][1] += f16hi(v.x);
                acc[u][2] += f16lo(v.y); acc[u][3] += f16hi(v.y);
            }
        }
#pragma unroll
    for (int u = 0; u < 2; ++u) {
        const int g = gh * 2 + u;
        const int bd = 16 * g + ln;
        const int b = bd >> 6, d = bd & 63;
#pragma unroll
        for (int r = 0; r < 4; ++r) {
            const int j = jx * 64 + jt * 16 + 4 * q + r;
            const int idx = (b * NN + j) * DD + d;
            out[idx] = S[idx] + acc[u][r];
        }
    }
}

// ---------------------------------------------------------------------------
extern "C" void kernel_launch(void* const* d_in, const int* in_sizes, int n_in,
                              void* d_out, int out_size, void* d_ws, size_t ws_size,
                              hipStream_t stream) {
    const float* states = (const float*)d_in[0];  // [B,N,D]
    const float* prof   = (const float*)d_in[1];  // [B,N]
    const float* emb    = (const float*)d_in[2];  // [N,E]
    const float* W      = (const float*)d_in[3];  // [1,E,E]
    const float* bias   = (const float*)d_in[4];  // [1]
    float* out = (float*)d_out;

    short* P_bf = (short*)d_ws;                     // 1 MB
    short* U_bf = P_bf + NN * EE;                   // 1 MB
    _Float16* es16f = (_Float16*)(U_bf + NN * EE);  // 2 MB (fragment-major, g-paired)
    unsigned short* part = (unsigned short*)((short*)es16f + (size_t)NB * 64 * NN);  // 33.6 MB

    prep_kernel<<<256, 256, 0, stream>>>(emb, W, states, prof, P_bf, U_bf, es16f);
    transfer_kernel<<<dim3(128, ISPLIT), 256, 0, stream>>>(P_bf, U_bf, es16f, bias, part);
    reduce_kernel<<<dim3(128, 4), 256, 0, stream>>>(part, states, out);
}